// Round 1
// baseline (654.343 us; speedup 1.0000x reference)
//
#include <hip/hip_runtime.h>

// ---------- types ----------
typedef __bf16 bf16x8 __attribute__((ext_vector_type(8)));
typedef float  f32x4  __attribute__((ext_vector_type(4)));
typedef unsigned short u16;

typedef __attribute__((address_space(3))) unsigned lds_u32;
typedef __attribute__((address_space(1))) unsigned glob_u32;

// global->LDS direct DMA, 16B per lane. LDS dest is wave-uniform base; HW adds lane*16.
__device__ __forceinline__ void gll16(const void* g, void* l) {
  __builtin_amdgcn_global_load_lds(
      (const glob_u32*)(unsigned long long)g,
      (lds_u32*)(unsigned)(unsigned long long)l, 16, 0, 0);
}

__device__ __forceinline__ u16 cvt_bf16(float f) {
  union { float f; unsigned u; } c; c.f = f;
  unsigned u = c.u;
  return (u16)((u + 0x7FFFu + ((u >> 16) & 1u)) >> 16);
}

// ---------- weight transpose + f32->bf16 : W[K][N] -> WT[N][K] ----------
__global__ void __launch_bounds__(256) transpose_cvt(const float* __restrict__ W,
                                                     u16* __restrict__ WT,
                                                     int K, int N) {
  __shared__ float t[32][33];
  int n0 = blockIdx.x * 32, k0 = blockIdx.y * 32;
  int tx = threadIdx.x, ty = threadIdx.y;  // (32,8)
#pragma unroll
  for (int i = 0; i < 4; i++)
    t[ty + i * 8][tx] = W[(size_t)(k0 + ty + i * 8) * N + n0 + tx];
  __syncthreads();
#pragma unroll
  for (int i = 0; i < 4; i++)
    WT[(size_t)(n0 + ty + i * 8) * K + k0 + tx] = cvt_bf16(t[tx][ty + i * 8]);
}

// ---------- LayerNorm: x[row][1024] f32 -> xn bf16 ----------
__global__ void __launch_bounds__(256) ln_kernel(const float* __restrict__ x,
                                                 const float* __restrict__ g,
                                                 u16* __restrict__ xn) {
  int row = blockIdx.x, tid = threadIdx.x;
  const float4* xr = (const float4*)(x + (size_t)row * 1024);
  float4 v = xr[tid];
  float s  = v.x + v.y + v.z + v.w;
  float ss = v.x * v.x + v.y * v.y + v.z * v.z + v.w * v.w;
#pragma unroll
  for (int off = 32; off > 0; off >>= 1) {
    s  += __shfl_down(s, off);
    ss += __shfl_down(ss, off);
  }
  __shared__ float red[8];
  if ((tid & 63) == 0) { red[(tid >> 6) * 2] = s; red[(tid >> 6) * 2 + 1] = ss; }
  __syncthreads();
  s  = red[0] + red[2] + red[4] + red[6];
  ss = red[1] + red[3] + red[5] + red[7];
  float mean = s * (1.0f / 1024.0f);
  float var  = ss * (1.0f / 1024.0f) - mean * mean;
  float inv  = rsqrtf(var + 1e-5f);
  float4 gv = ((const float4*)g)[tid];
  unsigned p0 = (unsigned)cvt_bf16((v.x - mean) * inv * gv.x) |
                ((unsigned)cvt_bf16((v.y - mean) * inv * gv.y) << 16);
  unsigned p1 = (unsigned)cvt_bf16((v.z - mean) * inv * gv.z) |
                ((unsigned)cvt_bf16((v.w - mean) * inv * gv.w) << 16);
  uint2 o; o.x = p0; o.y = p1;
  *(uint2*)(xn + (size_t)row * 1024 + tid * 4) = o;
}

// ---------- GEMM: A[M,K] bf16 row-major  x  BT[N,K] bf16 row-major ----------
// 128x128 tile, BK=64, 4 waves each 64x64 (4x4 frags of 16x16x32).
// EPI 0: QKV epilogue (Q/K -> [B,H,N,64], V -> transposed [B,H,64,N]); EPI 1: f32 out.
template <int EPI>
__global__ void __launch_bounds__(256) gemm_bt(const u16* __restrict__ A,
                                               const u16* __restrict__ BT,
                                               u16* __restrict__ oQ, u16* __restrict__ oK,
                                               u16* __restrict__ oVt, float* __restrict__ oF,
                                               int M, int N, int K) {
  __shared__ u16 As[128 * 64];
  __shared__ u16 Bs[128 * 64];
  int tiles_n = N >> 7;
  int tm = blockIdx.x / tiles_n, tn = blockIdx.x % tiles_n;
  int tid = threadIdx.x, w = tid >> 6, l = tid & 63;
  int wr = w >> 1, wc = w & 1;
  f32x4 acc[4][4] = {};
  const u16* Abase = A + (size_t)(tm * 128) * K;
  const u16* Bbase = BT + (size_t)(tn * 128) * K;

  for (int k0 = 0; k0 < K; k0 += 64) {
    // stage A and B tiles: linear LDS dest, swizzled global source (involution XOR)
#pragma unroll
    for (int t = 0; t < 4; t++) {
      int gi  = t * 256 + tid;          // 16B granule index
      int o   = gi * 16;                // linear byte offset in tile
      int row = o >> 7;                 // 128B per row (BK=64 bf16)
      int sb  = o ^ ((row & 7) << 4);   // swizzled source byte
      int col = (sb >> 1) & 63;
      gll16(Abase + (size_t)row * K + k0 + col, (char*)As + t * 4096 + w * 1024);
      gll16(Bbase + (size_t)row * K + k0 + col, (char*)Bs + t * 4096 + w * 1024);
    }
    __syncthreads();
#pragma unroll
    for (int ks = 0; ks < 2; ks++) {
      bf16x8 af[4], bfr[4];
      int kb = ks * 64 + ((l >> 4) << 4);  // byte offset within row for this lane
#pragma unroll
      for (int m = 0; m < 4; m++) {
        int row  = wr * 64 + m * 16 + (l & 15);
        int byte = (row * 128 + kb) ^ ((l & 7) << 4);
        af[m] = *(const bf16x8*)((const char*)As + byte);
      }
#pragma unroll
      for (int n = 0; n < 4; n++) {
        int row  = wc * 64 + n * 16 + (l & 15);
        int byte = (row * 128 + kb) ^ ((l & 7) << 4);
        bfr[n] = *(const bf16x8*)((const char*)Bs + byte);
      }
#pragma unroll
      for (int m = 0; m < 4; m++)
#pragma unroll
        for (int n = 0; n < 4; n++)
          acc[m][n] = __builtin_amdgcn_mfma_f32_16x16x32_bf16(af[m], bfr[n], acc[m][n], 0, 0, 0);
    }
    __syncthreads();
  }

  // epilogue: C[row=(l>>4)*4+r][col=l&15] per 16x16 fragment (m89-verified layout)
#pragma unroll
  for (int m = 0; m < 4; m++)
#pragma unroll
    for (int n = 0; n < 4; n++)
#pragma unroll
      for (int r = 0; r < 4; r++) {
        int rt = tm * 128 + wr * 64 + m * 16 + ((l >> 4) << 2) + r;  // token row
        int c  = tn * 128 + wc * 64 + n * 16 + (l & 15);             // output col
        float v = acc[m][n][r];
        if constexpr (EPI == 0) {
          int b = rt >> 11, nn = rt & 2047;
          u16 bv = cvt_bf16(v);
          if (c < 1024) {
            int h = c >> 6, dh = c & 63;
            oQ[((((size_t)b * 16 + h) * 2048) + nn) * 64 + dh] = bv;
          } else if (c < 2048) {
            int c2 = c - 1024, h = c2 >> 6, dh = c2 & 63;
            oK[((((size_t)b * 16 + h) * 2048) + nn) * 64 + dh] = bv;
          } else {
            int c2 = c - 2048, h = c2 >> 6, dh = c2 & 63;
            oVt[((((size_t)b * 16 + h) * 64) + dh) * 2048 + nn] = bv;
          }
        } else {
          oF[(size_t)rt * 1024 + c] = v;
        }
      }
}

// ---------- causal flash attention ----------
// grid: (b*16+h)*16 + qtile ; block 256 = 4 waves, each wave 32 q-rows, KB=64.
__global__ void __launch_bounds__(256) attn_kernel(const u16* __restrict__ Q,
                                                   const u16* __restrict__ Kb,
                                                   const u16* __restrict__ Vt,
                                                   u16* __restrict__ Ao) {
  __shared__ u16 P[4][32 * 64];  // per-wave P tile, XOR-swizzled
  int bx = blockIdx.x;
  int qt = bx & 15;
  int bh = bx >> 4;  // b*16 + h
  int tid = threadIdx.x, w = tid >> 6, l = tid & 63;
  int q0 = qt * 128 + w * 32;
  const u16* Qb    = Q  + (size_t)bh * 2048 * 64;
  const u16* Kbase = Kb + (size_t)bh * 2048 * 64;
  const u16* Vbase = Vt + (size_t)bh * 64 * 2048;
  char* Pw = (char*)&P[w][0];

  // Q fragments held in registers for the whole kernel
  bf16x8 aq[2][2];
#pragma unroll
  for (int m = 0; m < 2; m++)
#pragma unroll
    for (int ks = 0; ks < 2; ks++)
      aq[m][ks] = *(const bf16x8*)(Qb + (size_t)(q0 + m * 16 + (l & 15)) * 64 + ks * 32 + ((l >> 4) << 3));

  f32x4 O[2][4] = {};
  float mrun[2][4], lrun[2][4];
#pragma unroll
  for (int m = 0; m < 2; m++)
#pragma unroll
    for (int r = 0; r < 4; r++) { mrun[m][r] = -INFINITY; lrun[m][r] = 0.f; }

  int nkb = 2 * qt + 2;  // uniform across waves; tail blocks are fully masked (inert)
  for (int kbi = 0; kbi < nkb; kbi++) {
    int k0 = kbi * 64;
    // ---- S = Q K^T ----
    bf16x8 bk[4][2];
#pragma unroll
    for (int nf = 0; nf < 4; nf++)
#pragma unroll
      for (int ks = 0; ks < 2; ks++)
        bk[nf][ks] = *(const bf16x8*)(Kbase + (size_t)(k0 + nf * 16 + (l & 15)) * 64 + ks * 32 + ((l >> 4) << 3));
    f32x4 s[2][4] = {};
#pragma unroll
    for (int m = 0; m < 2; m++)
#pragma unroll
      for (int nf = 0; nf < 4; nf++)
#pragma unroll
        for (int ks = 0; ks < 2; ks++)
          s[m][nf] = __builtin_amdgcn_mfma_f32_16x16x32_bf16(aq[m][ks], bk[nf][ks], s[m][nf], 0, 0, 0);

    // ---- scale + causal mask + online softmax ----
    int colb = k0 + (l & 15);
#pragma unroll
    for (int m = 0; m < 2; m++) {
      int rowb = q0 + m * 16 + ((l >> 4) << 2);
      float scl[4];
#pragma unroll
      for (int nf = 0; nf < 4; nf++) {
        int col = colb + nf * 16;
#pragma unroll
        for (int r = 0; r < 4; r++) {
          float v = s[m][nf][r] * 0.125f;
          if (col > rowb + r) v = -1e30f;
          s[m][nf][r] = v;
        }
      }
#pragma unroll
      for (int r = 0; r < 4; r++) {
        float mx = fmaxf(fmaxf(s[m][0][r], s[m][1][r]), fmaxf(s[m][2][r], s[m][3][r]));
        mx = fmaxf(mx, __shfl_xor(mx, 1));
        mx = fmaxf(mx, __shfl_xor(mx, 2));
        mx = fmaxf(mx, __shfl_xor(mx, 4));
        mx = fmaxf(mx, __shfl_xor(mx, 8));
        float mn = fmaxf(mrun[m][r], mx);
        float sc = __expf(mrun[m][r] - mn);
        mrun[m][r] = mn;
        float rs = 0.f;
#pragma unroll
        for (int nf = 0; nf < 4; nf++) {
          float p = __expf(s[m][nf][r] - mn);
          s[m][nf][r] = p;
          rs += p;
        }
        rs += __shfl_xor(rs, 1);
        rs += __shfl_xor(rs, 2);
        rs += __shfl_xor(rs, 4);
        rs += __shfl_xor(rs, 8);
        lrun[m][r] = lrun[m][r] * sc + rs;
        scl[r] = sc;
      }
#pragma unroll
      for (int nf = 0; nf < 4; nf++)
#pragma unroll
        for (int r = 0; r < 4; r++) O[m][nf][r] *= scl[r];
    }

    // ---- stage P (bf16, swizzled) ----
    __syncthreads();  // WAR: previous iteration's P reads done
#pragma unroll
    for (int m = 0; m < 2; m++)
#pragma unroll
      for (int nf = 0; nf < 4; nf++)
#pragma unroll
        for (int r = 0; r < 4; r++) {
          int row  = m * 16 + ((l >> 4) << 2) + r;
          int byte = (row * 128 + ((nf * 16 + (l & 15)) << 1)) ^ ((row & 7) << 4);
          *(u16*)(Pw + byte) = cvt_bf16(s[m][nf][r]);
        }
    __syncthreads();  // writes visible before reads

    // ---- O += P V ----
    bf16x8 bv[4][2];
#pragma unroll
    for (int nf = 0; nf < 4; nf++)
#pragma unroll
      for (int ks = 0; ks < 2; ks++)
        bv[nf][ks] = *(const bf16x8*)(Vbase + (size_t)(nf * 16 + (l & 15)) * 2048 + k0 + ks * 32 + ((l >> 4) << 3));
    bf16x8 pa[2][2];
#pragma unroll
    for (int m = 0; m < 2; m++)
#pragma unroll
      for (int ks = 0; ks < 2; ks++) {
        int row  = m * 16 + (l & 15);
        int byte = (row * 128 + ks * 64 + ((l >> 4) << 4)) ^ ((row & 7) << 4);
        pa[m][ks] = *(const bf16x8*)(Pw + byte);
      }
#pragma unroll
    for (int m = 0; m < 2; m++)
#pragma unroll
      for (int nf = 0; nf < 4; nf++)
#pragma unroll
        for (int ks = 0; ks < 2; ks++)
          O[m][nf] = __builtin_amdgcn_mfma_f32_16x16x32_bf16(pa[m][ks], bv[nf][ks], O[m][nf], 0, 0, 0);
  }

  // ---- write attn output [token][h*64+dh] bf16 ----
  int b = bh >> 4, h = bh & 15;
#pragma unroll
  for (int m = 0; m < 2; m++)
#pragma unroll
    for (int nf = 0; nf < 4; nf++)
#pragma unroll
      for (int r = 0; r < 4; r++) {
        int row = q0 + m * 16 + ((l >> 4) << 2) + r;
        int col = h * 64 + nf * 16 + (l & 15);
        float v = O[m][nf][r] / lrun[m][r];
        Ao[((size_t)b * 2048 + row) * 1024 + col] = cvt_bf16(v);
      }
}

// ---------- launch ----------
extern "C" void kernel_launch(void* const* d_in, const int* in_sizes, int n_in,
                              void* d_out, int out_size, void* d_ws, size_t ws_size,
                              hipStream_t stream) {
  const float* x   = (const float*)d_in[0];
  const float* g   = (const float*)d_in[1];
  const float* Wq  = (const float*)d_in[2];
  const float* Wkv = (const float*)d_in[3];
  const float* Wo  = (const float*)d_in[4];
  float* out = (float*)d_out;
  char* ws = (char*)d_ws;

  u16* WT  = (u16*)(ws);                 // [3072][1024] bf16 : rows 0..1023 Wq^T, 1024..3071 Wkv^T
  u16* WoT = (u16*)(ws + 6291456);       // [1024][1024]
  u16* xn  = (u16*)(ws + 8388608);       // [8192][1024]
  u16* Qb  = (u16*)(ws + 25165824);      // [B,H,N,64]
  u16* Kb  = (u16*)(ws + 41943040);      // [B,H,N,64]
  u16* Vt  = (u16*)(ws + 58720256);      // [B,H,64,N]
  u16* Ao  = (u16*)(ws + 75497472);      // [8192][1024]

  transpose_cvt<<<dim3(32, 32), dim3(32, 8), 0, stream>>>(Wq, WT, 1024, 1024);
  transpose_cvt<<<dim3(64, 32), dim3(32, 8), 0, stream>>>(Wkv, WT + 1024 * 1024, 1024, 2048);
  transpose_cvt<<<dim3(32, 32), dim3(32, 8), 0, stream>>>(Wo, WoT, 1024, 1024);
  ln_kernel<<<8192, 256, 0, stream>>>(x, g, xn);
  gemm_bt<0><<<64 * 24, 256, 0, stream>>>(xn, WT, Qb, Kb, Vt, nullptr, 8192, 3072, 1024);
  attn_kernel<<<1024, 256, 0, stream>>>(Qb, Kb, Vt, Ao);
  gemm_bt<1><<<64 * 8, 256, 0, stream>>>(Ao, WoT, nullptr, nullptr, nullptr, out, 8192, 1024, 1024);
}

// Round 2
// 367.128 us; speedup vs baseline: 1.7823x; 1.7823x over previous
//
#include <hip/hip_runtime.h>

// ---------- types ----------
typedef __bf16 bf16x8 __attribute__((ext_vector_type(8)));
typedef float  f32x4  __attribute__((ext_vector_type(4)));
typedef unsigned short u16;

typedef __attribute__((address_space(3))) unsigned lds_u32;
typedef __attribute__((address_space(1))) unsigned glob_u32;

// global->LDS direct DMA, 16B per lane. LDS dest is wave-uniform base; HW adds lane*16.
__device__ __forceinline__ void gll16(const void* g, void* l) {
  __builtin_amdgcn_global_load_lds(
      (const glob_u32*)(unsigned long long)g,
      (lds_u32*)(unsigned)(unsigned long long)l, 16, 0, 0);
}

__device__ __forceinline__ u16 cvt_bf16(float f) {
  union { float f; unsigned u; } c; c.f = f;
  unsigned u = c.u;
  return (u16)((u + 0x7FFFu + ((u >> 16) & 1u)) >> 16);
}

// ---------- weight transpose + f32->bf16 : W[K][N] -> WT[N][K] ----------
__global__ void __launch_bounds__(256) transpose_cvt(const float* __restrict__ W,
                                                     u16* __restrict__ WT,
                                                     int K, int N) {
  __shared__ float t[32][33];
  int n0 = blockIdx.x * 32, k0 = blockIdx.y * 32;
  int tx = threadIdx.x, ty = threadIdx.y;  // (32,8)
#pragma unroll
  for (int i = 0; i < 4; i++)
    t[ty + i * 8][tx] = W[(size_t)(k0 + ty + i * 8) * N + n0 + tx];
  __syncthreads();
#pragma unroll
  for (int i = 0; i < 4; i++)
    WT[(size_t)(n0 + ty + i * 8) * K + k0 + tx] = cvt_bf16(t[tx][ty + i * 8]);
}

// ---------- LayerNorm: x[row][1024] f32 -> xn bf16 ----------
__global__ void __launch_bounds__(256) ln_kernel(const float* __restrict__ x,
                                                 const float* __restrict__ g,
                                                 u16* __restrict__ xn) {
  int row = blockIdx.x, tid = threadIdx.x;
  const float4* xr = (const float4*)(x + (size_t)row * 1024);
  float4 v = xr[tid];
  float s  = v.x + v.y + v.z + v.w;
  float ss = v.x * v.x + v.y * v.y + v.z * v.z + v.w * v.w;
#pragma unroll
  for (int off = 32; off > 0; off >>= 1) {
    s  += __shfl_down(s, off);
    ss += __shfl_down(ss, off);
  }
  __shared__ float red[8];
  if ((tid & 63) == 0) { red[(tid >> 6) * 2] = s; red[(tid >> 6) * 2 + 1] = ss; }
  __syncthreads();
  s  = red[0] + red[2] + red[4] + red[6];
  ss = red[1] + red[3] + red[5] + red[7];
  float mean = s * (1.0f / 1024.0f);
  float var  = ss * (1.0f / 1024.0f) - mean * mean;
  float inv  = rsqrtf(var + 1e-5f);
  float4 gv = ((const float4*)g)[tid];
  unsigned p0 = (unsigned)cvt_bf16((v.x - mean) * inv * gv.x) |
                ((unsigned)cvt_bf16((v.y - mean) * inv * gv.y) << 16);
  unsigned p1 = (unsigned)cvt_bf16((v.z - mean) * inv * gv.z) |
                ((unsigned)cvt_bf16((v.w - mean) * inv * gv.w) << 16);
  uint2 o; o.x = p0; o.y = p1;
  *(uint2*)(xn + (size_t)row * 1024 + tid * 4) = o;
}

// ---------- GEMM: A[M,K] bf16 row-major  x  BT[N,K] bf16 row-major ----------
// 128x128 tile, BK=64, 4 waves each 64x64 (4x4 frags of 16x16x32).
// EPI 0: QKV epilogue (Q/K -> [B,H,N,64], V -> transposed [B,H,64,N]); EPI 1: f32 out.
template <int EPI>
__global__ void __launch_bounds__(256) gemm_bt(const u16* __restrict__ A,
                                               const u16* __restrict__ BT,
                                               u16* __restrict__ oQ, u16* __restrict__ oK,
                                               u16* __restrict__ oVt, float* __restrict__ oF,
                                               int M, int N, int K) {
  __shared__ u16 As[128 * 64];
  __shared__ u16 Bs[128 * 64];
  int tiles_n = N >> 7;
  int tm = blockIdx.x / tiles_n, tn = blockIdx.x % tiles_n;
  int tid = threadIdx.x, w = tid >> 6, l = tid & 63;
  int wr = w >> 1, wc = w & 1;
  f32x4 acc[4][4] = {};
  const u16* Abase = A + (size_t)(tm * 128) * K;
  const u16* Bbase = BT + (size_t)(tn * 128) * K;

  for (int k0 = 0; k0 < K; k0 += 64) {
    // stage A and B tiles: linear LDS dest, swizzled global source (involution XOR)
#pragma unroll
    for (int t = 0; t < 4; t++) {
      int gi  = t * 256 + tid;          // 16B granule index
      int o   = gi * 16;                // linear byte offset in tile
      int row = o >> 7;                 // 128B per row (BK=64 bf16)
      int sb  = o ^ ((row & 7) << 4);   // swizzled source byte
      int col = (sb >> 1) & 63;
      gll16(Abase + (size_t)row * K + k0 + col, (char*)As + t * 4096 + w * 1024);
      gll16(Bbase + (size_t)row * K + k0 + col, (char*)Bs + t * 4096 + w * 1024);
    }
    __syncthreads();
#pragma unroll
    for (int ks = 0; ks < 2; ks++) {
      bf16x8 af[4], bfr[4];
      int kb = ks * 64 + ((l >> 4) << 4);  // byte offset within row for this lane
#pragma unroll
      for (int m = 0; m < 4; m++) {
        int row  = wr * 64 + m * 16 + (l & 15);
        int byte = (row * 128 + kb) ^ ((l & 7) << 4);
        af[m] = *(const bf16x8*)((const char*)As + byte);
      }
#pragma unroll
      for (int n = 0; n < 4; n++) {
        int row  = wc * 64 + n * 16 + (l & 15);
        int byte = (row * 128 + kb) ^ ((l & 7) << 4);
        bfr[n] = *(const bf16x8*)((const char*)Bs + byte);
      }
#pragma unroll
      for (int m = 0; m < 4; m++)
#pragma unroll
        for (int n = 0; n < 4; n++)
          acc[m][n] = __builtin_amdgcn_mfma_f32_16x16x32_bf16(af[m], bfr[n], acc[m][n], 0, 0, 0);
    }
    __syncthreads();
  }

  // epilogue: C[row=(l>>4)*4+r][col=l&15] per 16x16 fragment (m89-verified layout)
#pragma unroll
  for (int m = 0; m < 4; m++)
#pragma unroll
    for (int n = 0; n < 4; n++)
#pragma unroll
      for (int r = 0; r < 4; r++) {
        int rt = tm * 128 + wr * 64 + m * 16 + ((l >> 4) << 2) + r;  // token row
        int c  = tn * 128 + wc * 64 + n * 16 + (l & 15);             // output col
        float v = acc[m][n][r];
        if constexpr (EPI == 0) {
          int b = rt >> 11, nn = rt & 2047;
          u16 bv = cvt_bf16(v);
          if (c < 1024) {
            int h = c >> 6, dh = c & 63;
            oQ[((((size_t)b * 16 + h) * 2048) + nn) * 64 + dh] = bv;
          } else if (c < 2048) {
            int c2 = c - 1024, h = c2 >> 6, dh = c2 & 63;
            oK[((((size_t)b * 16 + h) * 2048) + nn) * 64 + dh] = bv;
          } else {
            int c2 = c - 2048, h = c2 >> 6, dh = c2 & 63;
            oVt[((((size_t)b * 16 + h) * 64) + dh) * 2048 + nn] = bv;
          }
        } else {
          oF[(size_t)rt * 1024 + c] = v;
        }
      }
}

// ---------- causal flash attention ----------
// grid: 64 (b*h) x 32 pairs, 1 wave per block, NO barriers (P is wave-private).
// Wave-slot ws owns q-rows [ws*32, ws*32+32); needs (ws>>1)+1 key-blocks of 64.
// Pairing ws=p with ws=63-p makes every block exactly 33 key-block iterations.
__global__ void __launch_bounds__(64, 2) attn_kernel(const u16* __restrict__ Q,
                                                     const u16* __restrict__ Kb,
                                                     const u16* __restrict__ Vt,
                                                     u16* __restrict__ Ao) {
  __shared__ u16 P[32 * 64];  // wave-private P tile, XOR-swizzled
  int bx = blockIdx.x;
  int bh = bx >> 5;        // b*16 + h
  int pair = bx & 31;
  int l = threadIdx.x;
  const u16* Qb    = Q  + (size_t)bh * 2048 * 64;
  const u16* Kbase = Kb + (size_t)bh * 2048 * 64;
  const u16* Vbase = Vt + (size_t)bh * 64 * 2048;
  char* Pw = (char*)P;
  int b = bh >> 4, h = bh & 15;
  const float SCL = 0.125f * 1.44269504f;  // 1/sqrt(64) * log2(e)

#pragma unroll
  for (int seg = 0; seg < 2; seg++) {
    int ws = seg ? (63 - pair) : pair;
    int q0 = ws * 32;
    int nkb = (ws >> 1) + 1;

    // Q fragments in registers for this segment
    bf16x8 aq[2][2];
#pragma unroll
    for (int m = 0; m < 2; m++)
#pragma unroll
      for (int ks = 0; ks < 2; ks++)
        aq[m][ks] = *(const bf16x8*)(Qb + (size_t)(q0 + m * 16 + (l & 15)) * 64 + ks * 32 + ((l >> 4) << 3));

    f32x4 O[2][4] = {};
    float mrun[2][4], lrun[2][4];
#pragma unroll
    for (int m = 0; m < 2; m++)
#pragma unroll
      for (int r = 0; r < 4; r++) { mrun[m][r] = -1e30f; lrun[m][r] = 0.f; }

    // prefetch K-block 0
    bf16x8 bk[4][2], bkn[4][2];
#pragma unroll
    for (int nf = 0; nf < 4; nf++)
#pragma unroll
      for (int ks = 0; ks < 2; ks++)
        bk[nf][ks] = *(const bf16x8*)(Kbase + (size_t)(nf * 16 + (l & 15)) * 64 + ks * 32 + ((l >> 4) << 3));

    for (int kbi = 0; kbi < nkb; kbi++) {
      int k0 = kbi * 64;
      // issue V loads for this block early (consumed after softmax)
      bf16x8 bv[4][2];
#pragma unroll
      for (int nf = 0; nf < 4; nf++)
#pragma unroll
        for (int ks = 0; ks < 2; ks++)
          bv[nf][ks] = *(const bf16x8*)(Vbase + (size_t)(nf * 16 + (l & 15)) * 2048 + k0 + ks * 32 + ((l >> 4) << 3));
      // issue next K-block loads early (consumed next iteration)
      if (kbi + 1 < nkb) {
        int k1 = k0 + 64;
#pragma unroll
        for (int nf = 0; nf < 4; nf++)
#pragma unroll
          for (int ks = 0; ks < 2; ks++)
            bkn[nf][ks] = *(const bf16x8*)(Kbase + (size_t)(k1 + nf * 16 + (l & 15)) * 64 + ks * 32 + ((l >> 4) << 3));
      }

      // ---- S = Q K^T ----
      f32x4 s[2][4] = {};
#pragma unroll
      for (int m = 0; m < 2; m++)
#pragma unroll
        for (int nf = 0; nf < 4; nf++)
#pragma unroll
          for (int ks = 0; ks < 2; ks++)
            s[m][nf] = __builtin_amdgcn_mfma_f32_16x16x32_bf16(aq[m][ks], bk[nf][ks], s[m][nf], 0, 0, 0);

      // ---- scale (log2-domain) + causal mask + online softmax ----
      int colb = k0 + (l & 15);
#pragma unroll
      for (int m = 0; m < 2; m++) {
        int rowb = q0 + m * 16 + ((l >> 4) << 2);
        float scl[4];
#pragma unroll
        for (int nf = 0; nf < 4; nf++) {
          int col = colb + nf * 16;
#pragma unroll
          for (int r = 0; r < 4; r++) {
            float v = s[m][nf][r] * SCL;
            if (col > rowb + r) v = -1e30f;
            s[m][nf][r] = v;
          }
        }
#pragma unroll
        for (int r = 0; r < 4; r++) {
          float mx = fmaxf(fmaxf(s[m][0][r], s[m][1][r]), fmaxf(s[m][2][r], s[m][3][r]));
          mx = fmaxf(mx, __shfl_xor(mx, 1));
          mx = fmaxf(mx, __shfl_xor(mx, 2));
          mx = fmaxf(mx, __shfl_xor(mx, 4));
          mx = fmaxf(mx, __shfl_xor(mx, 8));
          float mn = fmaxf(mrun[m][r], mx);
          float sc = exp2f(mrun[m][r] - mn);
          mrun[m][r] = mn;
          float rs = 0.f;
#pragma unroll
          for (int nf = 0; nf < 4; nf++) {
            float p = exp2f(s[m][nf][r] - mn);
            s[m][nf][r] = p;
            rs += p;
          }
          rs += __shfl_xor(rs, 1);
          rs += __shfl_xor(rs, 2);
          rs += __shfl_xor(rs, 4);
          rs += __shfl_xor(rs, 8);
          lrun[m][r] = lrun[m][r] * sc + rs;
          scl[r] = sc;
        }
#pragma unroll
        for (int nf = 0; nf < 4; nf++)
#pragma unroll
          for (int r = 0; r < 4; r++) O[m][nf][r] *= scl[r];
      }

      // ---- stage P (bf16, swizzled; wave-private -> no barriers) ----
#pragma unroll
      for (int m = 0; m < 2; m++)
#pragma unroll
        for (int nf = 0; nf < 4; nf++)
#pragma unroll
          for (int r = 0; r < 4; r++) {
            int row  = m * 16 + ((l >> 4) << 2) + r;
            int byte = (row * 128 + ((nf * 16 + (l & 15)) << 1)) ^ ((row & 7) << 4);
            *(u16*)(Pw + byte) = cvt_bf16(s[m][nf][r]);
          }

      // ---- O += P V ----
      bf16x8 pa[2][2];
#pragma unroll
      for (int m = 0; m < 2; m++)
#pragma unroll
        for (int ks = 0; ks < 2; ks++) {
          int row  = m * 16 + (l & 15);
          int byte = (row * 128 + ks * 64 + ((l >> 4) << 4)) ^ ((row & 7) << 4);
          pa[m][ks] = *(const bf16x8*)(Pw + byte);
        }
#pragma unroll
      for (int m = 0; m < 2; m++)
#pragma unroll
        for (int nf = 0; nf < 4; nf++)
#pragma unroll
          for (int ks = 0; ks < 2; ks++)
            O[m][nf] = __builtin_amdgcn_mfma_f32_16x16x32_bf16(pa[m][ks], bv[nf][ks], O[m][nf], 0, 0, 0);

      // rotate prefetched K
#pragma unroll
      for (int nf = 0; nf < 4; nf++)
#pragma unroll
        for (int ks = 0; ks < 2; ks++) bk[nf][ks] = bkn[nf][ks];
    }

    // ---- write attn output [token][h*64+dh] bf16 ----
#pragma unroll
    for (int m = 0; m < 2; m++)
#pragma unroll
      for (int r = 0; r < 4; r++) {
        float rinv = 1.0f / lrun[m][r];
#pragma unroll
        for (int nf = 0; nf < 4; nf++) {
          int row = q0 + m * 16 + ((l >> 4) << 2) + r;
          int col = h * 64 + nf * 16 + (l & 15);
          Ao[((size_t)b * 2048 + row) * 1024 + col] = cvt_bf16(O[m][nf][r] * rinv);
        }
      }
  }
}

// ---------- launch ----------
extern "C" void kernel_launch(void* const* d_in, const int* in_sizes, int n_in,
                              void* d_out, int out_size, void* d_ws, size_t ws_size,
                              hipStream_t stream) {
  const float* x   = (const float*)d_in[0];
  const float* g   = (const float*)d_in[1];
  const float* Wq  = (const float*)d_in[2];
  const float* Wkv = (const float*)d_in[3];
  const float* Wo  = (const float*)d_in[4];
  float* out = (float*)d_out;
  char* ws = (char*)d_ws;

  u16* WT  = (u16*)(ws);                 // [3072][1024] bf16 : rows 0..1023 Wq^T, 1024..3071 Wkv^T
  u16* WoT = (u16*)(ws + 6291456);       // [1024][1024]
  u16* xn  = (u16*)(ws + 8388608);       // [8192][1024]
  u16* Qb  = (u16*)(ws + 25165824);      // [B,H,N,64]
  u16* Kb  = (u16*)(ws + 41943040);      // [B,H,N,64]
  u16* Vt  = (u16*)(ws + 58720256);      // [B,H,64,N]
  u16* Ao  = (u16*)(ws + 75497472);      // [8192][1024]

  transpose_cvt<<<dim3(32, 32), dim3(32, 8), 0, stream>>>(Wq, WT, 1024, 1024);
  transpose_cvt<<<dim3(64, 32), dim3(32, 8), 0, stream>>>(Wkv, WT + 1024 * 1024, 1024, 2048);
  transpose_cvt<<<dim3(32, 32), dim3(32, 8), 0, stream>>>(Wo, WoT, 1024, 1024);
  ln_kernel<<<8192, 256, 0, stream>>>(x, g, xn);
  gemm_bt<0><<<64 * 24, 256, 0, stream>>>(xn, WT, Qb, Kb, Vt, nullptr, 8192, 3072, 1024);
  attn_kernel<<<2048, 64, 0, stream>>>(Qb, Kb, Vt, Ao);
  gemm_bt<1><<<64 * 8, 256, 0, stream>>>(Ao, WoT, nullptr, nullptr, nullptr, out, 8192, 1024, 1024);
}

// Round 4
// 318.498 us; speedup vs baseline: 2.0545x; 1.1527x over previous
//
#include <hip/hip_runtime.h>

// ---------- types ----------
typedef __bf16 bf16x8 __attribute__((ext_vector_type(8)));
typedef float  f32x4  __attribute__((ext_vector_type(4)));
typedef unsigned short u16;

typedef __attribute__((address_space(3))) unsigned lds_u32;
typedef __attribute__((address_space(1))) unsigned glob_u32;

__device__ __forceinline__ void gll16(const void* g, void* l) {
  __builtin_amdgcn_global_load_lds(
      (const glob_u32*)(unsigned long long)g,
      (lds_u32*)(unsigned)(unsigned long long)l, 16, 0, 0);
}

__device__ __forceinline__ u16 cvt_bf16(float f) {
  union { float f; unsigned u; } c; c.f = f;
  unsigned u = c.u;
  return (u16)((u + 0x7FFFu + ((u >> 16) & 1u)) >> 16);
}

#define QSCALE 0.18033688011112042f  /* 0.125 * log2(e) */

// ---------- weight transpose + f32->bf16 : W[K][N] -> WT[N][K] ----------
__global__ void __launch_bounds__(256) transpose_cvt(const float* __restrict__ W,
                                                     u16* __restrict__ WT,
                                                     int K, int N) {
  __shared__ float t[32][33];
  int n0 = blockIdx.x * 32, k0 = blockIdx.y * 32;
  int tx = threadIdx.x, ty = threadIdx.y;  // (32,8)
#pragma unroll
  for (int i = 0; i < 4; i++)
    t[ty + i * 8][tx] = W[(size_t)(k0 + ty + i * 8) * N + n0 + tx];
  __syncthreads();
#pragma unroll
  for (int i = 0; i < 4; i++)
    WT[(size_t)(n0 + ty + i * 8) * K + k0 + tx] = cvt_bf16(t[tx][ty + i * 8]);
}

// ---------- LayerNorm: x[row][1024] f32 -> xn bf16 ----------
__global__ void __launch_bounds__(256) ln_kernel(const float* __restrict__ x,
                                                 const float* __restrict__ g,
                                                 u16* __restrict__ xn) {
  int row = blockIdx.x, tid = threadIdx.x;
  const float4* xr = (const float4*)(x + (size_t)row * 1024);
  float4 v = xr[tid];
  float s  = v.x + v.y + v.z + v.w;
  float ss = v.x * v.x + v.y * v.y + v.z * v.z + v.w * v.w;
#pragma unroll
  for (int off = 32; off > 0; off >>= 1) {
    s  += __shfl_down(s, off);
    ss += __shfl_down(ss, off);
  }
  __shared__ float red[8];
  if ((tid & 63) == 0) { red[(tid >> 6) * 2] = s; red[(tid >> 6) * 2 + 1] = ss; }
  __syncthreads();
  s  = red[0] + red[2] + red[4] + red[6];
  ss = red[1] + red[3] + red[5] + red[7];
  float mean = s * (1.0f / 1024.0f);
  float var  = ss * (1.0f / 1024.0f) - mean * mean;
  float inv  = rsqrtf(var + 1e-5f);
  float4 gv = ((const float4*)g)[tid];
  unsigned p0 = (unsigned)cvt_bf16((v.x - mean) * inv * gv.x) |
                ((unsigned)cvt_bf16((v.y - mean) * inv * gv.y) << 16);
  unsigned p1 = (unsigned)cvt_bf16((v.z - mean) * inv * gv.z) |
                ((unsigned)cvt_bf16((v.w - mean) * inv * gv.w) << 16);
  uint2 o; o.x = p0; o.y = p1;
  *(uint2*)(xn + (size_t)row * 1024 + tid * 4) = o;
}

// ---------- GEMM: A[M,K] bf16 row-major  x  BT[N,K] bf16 row-major ----------
// 128x128 tile, BK=64, 4 waves each 64x64 (4x4 frags of 16x16x32).
// EPI 0: QKV epilogue via LDS re-stage (Q pre-scaled by QSCALE; Q/K -> [B,H,N,64],
//        V -> transposed [B,H,64,N], all coalesced uint4); EPI 1: f32 direct out.
template <int EPI>
__global__ void __launch_bounds__(256) gemm_bt(const u16* __restrict__ A,
                                               const u16* __restrict__ BT,
                                               u16* __restrict__ oQ, u16* __restrict__ oK,
                                               u16* __restrict__ oVt, float* __restrict__ oF,
                                               int M, int N, int K) {
  __shared__ u16 smem[128 * 128];  // main loop: As(16KB)+Bs(16KB); epilogue: C-stage (32KB)
  u16* As = smem;
  u16* Bs = smem + 128 * 64;
  int tiles_n = N >> 7;
  // XCD-aware swizzle: consecutive logical tiles land on the same XCD (A-panel L2 reuse)
  int cpx = gridDim.x >> 3;
  int wg  = (int)blockIdx.x;
  int swz = (wg & 7) * cpx + (wg >> 3);
  int tm = swz / tiles_n, tn = swz % tiles_n;
  int tid = threadIdx.x, w = tid >> 6, l = tid & 63;
  int wr = w >> 1, wc = w & 1;
  f32x4 acc[4][4] = {};
  const u16* Abase = A + (size_t)(tm * 128) * K;
  const u16* Bbase = BT + (size_t)(tn * 128) * K;

  for (int k0 = 0; k0 < K; k0 += 64) {
#pragma unroll
    for (int t = 0; t < 4; t++) {
      int gi  = t * 256 + tid;
      int o   = gi * 16;
      int row = o >> 7;
      int sb  = o ^ ((row & 7) << 4);
      int col = (sb >> 1) & 63;
      gll16(Abase + (size_t)row * K + k0 + col, (char*)As + t * 4096 + w * 1024);
      gll16(Bbase + (size_t)row * K + k0 + col, (char*)Bs + t * 4096 + w * 1024);
    }
    __syncthreads();
#pragma unroll
    for (int ks = 0; ks < 2; ks++) {
      bf16x8 af[4], bfr[4];
      int kb = ks * 64 + ((l >> 4) << 4);
#pragma unroll
      for (int m = 0; m < 4; m++) {
        int row  = wr * 64 + m * 16 + (l & 15);
        int byte = (row * 128 + kb) ^ ((l & 7) << 4);
        af[m] = *(const bf16x8*)((const char*)As + byte);
      }
#pragma unroll
      for (int n = 0; n < 4; n++) {
        int row  = wc * 64 + n * 16 + (l & 15);
        int byte = (row * 128 + kb) ^ ((l & 7) << 4);
        bfr[n] = *(const bf16x8*)((const char*)Bs + byte);
      }
#pragma unroll
      for (int m = 0; m < 4; m++)
#pragma unroll
        for (int n = 0; n < 4; n++)
          acc[m][n] = __builtin_amdgcn_mfma_f32_16x16x32_bf16(af[m], bfr[n], acc[m][n], 0, 0, 0);
    }
    __syncthreads();
  }

  if constexpr (EPI == 0) {
    int c_base = tn * 128;
    bool isV = (c_base >= 2048);
    float qs = (c_base < 1024) ? QSCALE : 1.0f;
    // stage C tile to LDS (V transposed), XOR-swizzled
#pragma unroll
    for (int m = 0; m < 4; m++)
#pragma unroll
      for (int n = 0; n < 4; n++)
#pragma unroll
        for (int r = 0; r < 4; r++) {
          int rt2 = wr * 64 + m * 16 + ((l >> 4) << 2) + r;
          int c2  = wc * 64 + n * 16 + (l & 15);
          u16 bv16 = cvt_bf16(acc[m][n][r] * qs);
          int byte = isV ? ((c2 * 256 + rt2 * 2) ^ ((c2 & 7) << 4))
                         : ((rt2 * 256 + c2 * 2) ^ ((rt2 & 7) << 4));
          *(u16*)((char*)smem + byte) = bv16;
        }
    __syncthreads();
    int b = (tm * 128) >> 11;
    int nbase = (tm * 128) & 2047;
#pragma unroll
    for (int i = 0; i < 8; i++) {
      int ch = i * 256 + tid;
      int row = ch >> 4, off = ch & 15;
      uint4 d = *(const uint4*)((const char*)smem + ((row * 256 + off * 16) ^ ((row & 7) << 4)));
      if (isV) {
        int dh = row & 63;
        int h  = ((c_base - 2048) >> 6) + (row >> 6);
        *(uint4*)(oVt + ((((size_t)b * 16 + h) * 64) + dh) * 2048 + nbase + off * 8) = d;
      } else {
        int cg = c_base + off * 8;
        int nn = nbase + row;
        if (cg < 1024) {
          int h = cg >> 6, dh0 = cg & 63;
          *(uint4*)(oQ + ((((size_t)b * 16 + h) * 2048) + nn) * 64 + dh0) = d;
        } else {
          int c2g = cg - 1024, h = c2g >> 6, dh0 = c2g & 63;
          *(uint4*)(oK + ((((size_t)b * 16 + h) * 2048) + nn) * 64 + dh0) = d;
        }
      }
    }
  } else {
#pragma unroll
    for (int m = 0; m < 4; m++)
#pragma unroll
      for (int n = 0; n < 4; n++)
#pragma unroll
        for (int r = 0; r < 4; r++) {
          int rt = tm * 128 + wr * 64 + m * 16 + ((l >> 4) << 2) + r;
          int c  = tn * 128 + wc * 64 + n * 16 + (l & 15);
          oF[(size_t)rt * 1024 + c] = acc[m][n][r];
        }
  }
}

// ---------- causal flash attention ----------
// grid 2048, 1 wave/block, no barriers. XCD swizzle: all 32 pair-blocks of a head
// share one XCD's L2 (512KB K/V working set, streamed head-by-head).
// Q is pre-scaled by 0.125*log2e -> scores already log2-domain.
// Defer-max (THR=8): deferred iterations skip max-reduce/rescale entirely.
__global__ void __launch_bounds__(64, 2) attn_kernel(const u16* __restrict__ Q,
                                                     const u16* __restrict__ Kb,
                                                     const u16* __restrict__ Vt,
                                                     u16* __restrict__ Ao) {
  __shared__ u16 P[32 * 64];
  int bx = blockIdx.x;
  int bh = ((bx & 7) << 3) | (bx >> 8);  // b*16+h, pinned to XCD = bx&7
  int pair = (bx >> 3) & 31;
  int l = threadIdx.x;
  const u16* Qb    = Q  + (size_t)bh * 2048 * 64;
  const u16* Kbase = Kb + (size_t)bh * 2048 * 64;
  const u16* Vbase = Vt + (size_t)bh * 64 * 2048;
  char* Pw = (char*)P;
  int b = bh >> 4, h = bh & 15;

#pragma unroll
  for (int seg = 0; seg < 2; seg++) {
    int ws = seg ? (63 - pair) : pair;
    int q0 = ws * 32;
    int nkb = (ws >> 1) + 1;

    bf16x8 aq[2][2];
#pragma unroll
    for (int m = 0; m < 2; m++)
#pragma unroll
      for (int ks = 0; ks < 2; ks++)
        aq[m][ks] = *(const bf16x8*)(Qb + (size_t)(q0 + m * 16 + (l & 15)) * 64 + ks * 32 + ((l >> 4) << 3));

    f32x4 O[2][4] = {};
    float mrun[2][4], lpart[2][4];
#pragma unroll
    for (int m = 0; m < 2; m++)
#pragma unroll
      for (int r = 0; r < 4; r++) { mrun[m][r] = -1e30f; lpart[m][r] = 0.f; }

    bf16x8 bk[4][2], bkn[4][2];
#pragma unroll
    for (int nf = 0; nf < 4; nf++)
#pragma unroll
      for (int ks = 0; ks < 2; ks++)
        bk[nf][ks] = *(const bf16x8*)(Kbase + (size_t)(nf * 16 + (l & 15)) * 64 + ks * 32 + ((l >> 4) << 3));

    for (int kbi = 0; kbi < nkb; kbi++) {
      int k0 = kbi * 64;
      bf16x8 bv[4][2];
#pragma unroll
      for (int nf = 0; nf < 4; nf++)
#pragma unroll
        for (int ks = 0; ks < 2; ks++)
          bv[nf][ks] = *(const bf16x8*)(Vbase + (size_t)(nf * 16 + (l & 15)) * 2048 + k0 + ks * 32 + ((l >> 4) << 3));
      if (kbi + 1 < nkb) {
        int k1 = k0 + 64;
#pragma unroll
        for (int nf = 0; nf < 4; nf++)
#pragma unroll
          for (int ks = 0; ks < 2; ks++)
            bkn[nf][ks] = *(const bf16x8*)(Kbase + (size_t)(k1 + nf * 16 + (l & 15)) * 64 + ks * 32 + ((l >> 4) << 3));
      }

      // ---- S = Q K^T (already log2-domain) ----
      f32x4 s[2][4] = {};
#pragma unroll
      for (int m = 0; m < 2; m++)
#pragma unroll
        for (int nf = 0; nf < 4; nf++)
#pragma unroll
          for (int ks = 0; ks < 2; ks++)
            s[m][nf] = __builtin_amdgcn_mfma_f32_16x16x32_bf16(aq[m][ks], bk[nf][ks], s[m][nf], 0, 0, 0);

      // ---- causal mask: only the last key-block intersects the diagonal ----
      if (kbi == nkb - 1) {
        int colb = k0 + (l & 15);
#pragma unroll
        for (int m = 0; m < 2; m++) {
          int rowb = q0 + m * 16 + ((l >> 4) << 2);
#pragma unroll
          for (int nf = 0; nf < 4; nf++) {
            int col = colb + nf * 16;
#pragma unroll
            for (int r = 0; r < 4; r++)
              if (col > rowb + r) s[m][nf][r] = -1e30f;
          }
        }
      }

      // ---- defer-max check (per-lane local max, wave vote) ----
      float lmx[2][4];
      bool need = false;
#pragma unroll
      for (int m = 0; m < 2; m++)
#pragma unroll
        for (int r = 0; r < 4; r++) {
          lmx[m][r] = fmaxf(fmaxf(s[m][0][r], s[m][1][r]), fmaxf(s[m][2][r], s[m][3][r]));
          need |= (lmx[m][r] > mrun[m][r] + 8.0f);
        }
      if (__any(need)) {
#pragma unroll
        for (int m = 0; m < 2; m++)
#pragma unroll
          for (int r = 0; r < 4; r++) {
            float mx = lmx[m][r];
            mx = fmaxf(mx, __shfl_xor(mx, 1));
            mx = fmaxf(mx, __shfl_xor(mx, 2));
            mx = fmaxf(mx, __shfl_xor(mx, 4));
            mx = fmaxf(mx, __shfl_xor(mx, 8));
            float mn = fmaxf(mrun[m][r], mx);
            float sc = __builtin_amdgcn_exp2f(mrun[m][r] - mn);
            mrun[m][r] = mn;
            lpart[m][r] *= sc;
#pragma unroll
            for (int nf = 0; nf < 4; nf++) O[m][nf][r] *= sc;
          }
      }

      // ---- P = exp2(s - mrun); per-lane partial row-sum; stage P to LDS ----
#pragma unroll
      for (int m = 0; m < 2; m++)
#pragma unroll
        for (int r = 0; r < 4; r++) {
          int rowl = m * 16 + ((l >> 4) << 2) + r;
          float ps = 0.f;
#pragma unroll
          for (int nf = 0; nf < 4; nf++) {
            float p = __builtin_amdgcn_exp2f(s[m][nf][r] - mrun[m][r]);
            ps += p;
            int byte = (rowl * 128 + ((nf * 16 + (l & 15)) << 1)) ^ ((rowl & 7) << 4);
            *(u16*)(Pw + byte) = cvt_bf16(p);
          }
          lpart[m][r] += ps;
        }

      // ---- O += P V ----
      bf16x8 pa[2][2];
#pragma unroll
      for (int m = 0; m < 2; m++)
#pragma unroll
        for (int ks = 0; ks < 2; ks++) {
          int row  = m * 16 + (l & 15);
          int byte = (row * 128 + ks * 64 + ((l >> 4) << 4)) ^ ((row & 7) << 4);
          pa[m][ks] = *(const bf16x8*)(Pw + byte);
        }
#pragma unroll
      for (int m = 0; m < 2; m++)
#pragma unroll
        for (int nf = 0; nf < 4; nf++)
#pragma unroll
          for (int ks = 0; ks < 2; ks++)
            O[m][nf] = __builtin_amdgcn_mfma_f32_16x16x32_bf16(pa[m][ks], bv[nf][ks], O[m][nf], 0, 0, 0);

#pragma unroll
      for (int nf = 0; nf < 4; nf++)
#pragma unroll
        for (int ks = 0; ks < 2; ks++) bk[nf][ks] = bkn[nf][ks];
    }

    // ---- final row-sum reduce + output ----
#pragma unroll
    for (int m = 0; m < 2; m++)
#pragma unroll
      for (int r = 0; r < 4; r++) {
        float ls = lpart[m][r];
        ls += __shfl_xor(ls, 1);
        ls += __shfl_xor(ls, 2);
        ls += __shfl_xor(ls, 4);
        ls += __shfl_xor(ls, 8);
        float rinv = 1.0f / ls;
        int row = q0 + m * 16 + ((l >> 4) << 2) + r;
#pragma unroll
        for (int nf = 0; nf < 4; nf++) {
          int col = h * 64 + nf * 16 + (l & 15);
          Ao[((size_t)b * 2048 + row) * 1024 + col] = cvt_bf16(O[m][nf][r] * rinv);
        }
      }
  }
}

// ---------- launch ----------
extern "C" void kernel_launch(void* const* d_in, const int* in_sizes, int n_in,
                              void* d_out, int out_size, void* d_ws, size_t ws_size,
                              hipStream_t stream) {
  const float* x   = (const float*)d_in[0];
  const float* g   = (const float*)d_in[1];
  const float* Wq  = (const float*)d_in[2];
  const float* Wkv = (const float*)d_in[3];
  const float* Wo  = (const float*)d_in[4];
  float* out = (float*)d_out;
  char* ws = (char*)d_ws;

  u16* WT  = (u16*)(ws);                 // [3072][1024] bf16
  u16* WoT = (u16*)(ws + 6291456);       // [1024][1024]
  u16* xn  = (u16*)(ws + 8388608);       // [8192][1024]
  u16* Qb  = (u16*)(ws + 25165824);      // [B,H,N,64] (pre-scaled)
  u16* Kb  = (u16*)(ws + 41943040);      // [B,H,N,64]
  u16* Vt  = (u16*)(ws + 58720256);      // [B,H,64,N]
  u16* Ao  = (u16*)(ws + 75497472);      // [8192][1024]

  transpose_cvt<<<dim3(32, 32), dim3(32, 8), 0, stream>>>(Wq, WT, 1024, 1024);
  transpose_cvt<<<dim3(64, 32), dim3(32, 8), 0, stream>>>(Wkv, WT + 1024 * 1024, 1024, 2048);
  transpose_cvt<<<dim3(32, 32), dim3(32, 8), 0, stream>>>(Wo, WoT, 1024, 1024);
  ln_kernel<<<8192, 256, 0, stream>>>(x, g, xn);
  gemm_bt<0><<<64 * 24, 256, 0, stream>>>(xn, WT, Qb, Kb, Vt, nullptr, 8192, 3072, 1024);
  attn_kernel<<<2048, 64, 0, stream>>>(Qb, Kb, Vt, Ao);
  gemm_bt<1><<<64 * 8, 256, 0, stream>>>(Ao, WoT, nullptr, nullptr, nullptr, out, 8192, 1024, 1024);
}